// Round 4
// baseline (1997.374 us; speedup 1.0000x reference)
//
#include <hip/hip_runtime.h>

// IterativeGatedConv2D: 8 iterations of
//   g  = circ_depthwise_conv7x7(h, Wg); ht = circ_depthwise_conv7x7(h, Wh)
//   h  = h + sigmoid(g) * (ht - h)
// Layout: (B=8, H=256, W=256, C=64) channels-last fp32.
//
// R7: ROLE-SPLIT WAVES — one conv per wave, weights in SGPRs, live set <= 64.
//  - R5/R6 post-mortem: any design with ~90+ live vector values gets AGPR
//    parking (R6: VGPR_Count=64 vs ~95 live -> 92us VALU busy vs ~46us real).
//    The allocator will not give this kernel a large arch-VGPR budget.
//    Fix by construction: block = 8 waves = 4 channels x {gate, hidden} role.
//    Each wave: ONE conv, 49 weights in SGPRs (readfirstlane; v_fmac v,s,v
//    reads 1 SGPR: legal), acc[2][8]=16 VGPRs. Live ~52 <= 64 ->
//    __launch_bounds__(512,8) (cap 64), up to 8 waves/SIMD, zero parking.
//  - z handoff: gate wave sigmoid -> 16KB LDS exchange (overlays the tile
//    region after the sweep barrier); hidden wave blends with its in-reg ctr,
//    writes hn to transpose buffer; all 512 threads float4 gather-store
//    (256B-lane-stride stores measured only +12% write overhead in R6).
//  - Cost model: VALU/wave ~2030 cyc (784 FMA*2 + staging + epilogue) ->
//    ~55us/step issue; LDS ~50us (taps read 2x, but conflict ~4dw/bank);
//    HBM 25-35us (L3 absorbs ping-pong reads). 32 waves/CU overlap -> ~80us.
//  - Tripwires: WRITE_SIZE >> 147456 KB => spills returned; VGPR > 64 =>
//    launch_bounds ignored; dur >120us => theory wrong, pull disasm.
// Kept: XCD remap (cg fastest within an XCD chunk -> halo + store lines
//    shared in that XCD's L2), single-sweep sliding window, float4 staging.

#define HH 256
#define WW 256
#define CC 64
#define TH 8              // output rows per block
#define BC 128            // output cols per block (2 per lane)
#define LHT (TH + 6)      // 14
#define LWT (BC + 6)      // 134
#define PLANE (LHT * LWT) // 1876 floats per channel plane
#define ZOFF 0            // z exchange overlays planes after sweep
#define HOFF 4096         // hn transpose buffer (floats)
#define LDS_FLOATS 8192   // 32768 B -> 4-5 blocks/CU; wave cap binds at 4

__global__ __launch_bounds__(512, 8) void gated_step(
    const float* __restrict__ src,
    const float* __restrict__ wg_g,
    const float* __restrict__ wh_g,
    float* __restrict__ dst)
{
    __shared__ float lds[LDS_FLOATS];

    const int tid  = threadIdx.x;
    const int x    = tid & 63;                                 // lane = col pair
    const int w    = __builtin_amdgcn_readfirstlane(tid >> 6); // wave 0..7
    const int cw   = w & 3;                                    // channel-in-block
    const int role = w >> 2;                                   // 0=gate 1=hidden

    // XCD remap: 8192 blocks, 1024-chunk per XCD = one batch image; cg is the
    // fastest field so the 16 channel-group blocks of a tile share L2 lines.
    const int id  = (int)blockIdx.x;
    const int nid = ((id & 7) << 10) | (id >> 3);
    const int cg  = nid & 15;
    const int xs  = (nid >> 4) & 1;
    const int ys  = (nid >> 5) & 31;
    const int b   = nid >> 10;
    const int x0  = xs * BC;
    const int y0  = ys * TH;
    const int ch  = (cg << 2) | cw;   // wave-uniform channel

    // ---- stage input tile into 4 channel planes (float4 gathers) ----
    const float4* __restrict__ src4 = reinterpret_cast<const float4*>(src);
    for (int k = tid; k < PLANE; k += 512) {
        int col = k % LWT;
        int row = k / LWT;
        int gy = (y0 + row - 3) & 255;
        int gx = (x0 + col - 3) & 255;
        float4 v4 = src4[((((b << 8) + gy) << 8) + gx) * 16 + cg];
        lds[0 * PLANE + k] = v4.x;
        lds[1 * PLANE + k] = v4.y;
        lds[2 * PLANE + k] = v4.z;
        lds[3 * PLANE + k] = v4.w;
    }

    // ---- this wave's 49 weights -> SGPRs (forced via readfirstlane) ----
    const float* __restrict__ tbl = role ? wh_g : wg_g;
    float sw[49];
    #pragma unroll
    for (int t = 0; t < 49; ++t)
        sw[t] = __int_as_float(
            __builtin_amdgcn_readfirstlane(__float_as_int(tbl[ch * 49 + t])));

    __syncthreads();

    // ---- sliding-window conv: ONE conv, 2 cols x 8 rows per lane ----
    const float* plane = &lds[cw * PLANE];
    float acc[2][TH];
    #pragma unroll
    for (int r = 0; r < TH; ++r) { acc[0][r] = 0.0f; acc[1][r] = 0.0f; }
    float ctr0[TH], ctr1[TH]; // hidden role only (wave-uniform guard)

    #pragma unroll
    for (int iy = 0; iy < LHT; ++iy) {
        float v[8]; // taps for cols 2x .. 2x+7
        const float* rowp = plane + iy * LWT + 2 * x;
        #pragma unroll
        for (int m = 0; m < 4; ++m) {
            float2 t2 = *reinterpret_cast<const float2*>(rowp + 2 * m);
            v[2 * m]     = t2.x;
            v[2 * m + 1] = t2.y;
        }
        if (role && iy >= 3 && iy < 3 + TH) { // center taps = h itself
            ctr0[iy - 3] = v[3];
            ctr1[iy - 3] = v[4];
        }
        #pragma unroll
        for (int r = 0; r < TH; ++r) {
            const int i = r + 6 - iy;          // kernel row
            if (i >= 0 && i <= 6) {
                #pragma unroll
                for (int jv = 0; jv < 7; ++jv) {
                    const float a = sw[i * 7 + (6 - jv)]; // SGPR operand
                    acc[0][r] = fmaf(a, v[jv],     acc[0][r]);
                    acc[1][r] = fmaf(a, v[jv + 1], acc[1][r]);
                }
            }
        }
    }

    __syncthreads(); // A: all waves done reading planes; overlay is now safe

    if (role == 0) {
        // gate: z = sigmoid(acc) -> exchange buffer [cw][r][128]
        #pragma unroll
        for (int r = 0; r < TH; ++r) {
            float e0 = __expf(-acc[0][r]);
            float e1 = __expf(-acc[1][r]);
            float2 z;
            z.x = __builtin_amdgcn_rcpf(1.0f + e0);
            z.y = __builtin_amdgcn_rcpf(1.0f + e1);
            *reinterpret_cast<float2*>(&lds[ZOFF + cw * 1024 + r * 128 + 2 * x]) = z;
        }
    }
    __syncthreads(); // B: z visible

    if (role == 1) {
        // hidden: hn = ctr + z*(ht - ctr) -> transpose buffer [cw][r][128]
        #pragma unroll
        for (int r = 0; r < TH; ++r) {
            float2 z = *reinterpret_cast<const float2*>(
                &lds[ZOFF + cw * 1024 + r * 128 + 2 * x]);
            float2 hn;
            hn.x = fmaf(z.x, acc[0][r] - ctr0[r], ctr0[r]);
            hn.y = fmaf(z.y, acc[1][r] - ctr1[r], ctr1[r]);
            *reinterpret_cast<float2*>(&lds[HOFF + cw * 1024 + r * 128 + 2 * x]) = hn;
        }
    }
    __syncthreads(); // C: hn visible

    // ---- coalesced-ish float4 stores: 2 per thread ----
    float4* __restrict__ dst4 = reinterpret_cast<float4*>(dst);
    #pragma unroll
    for (int k2 = 0; k2 < 2; ++k2) {
        int pos = tid + k2 * 512;      // 0..1023
        int c2  = pos & 127;
        int r   = pos >> 7;
        float4 o;
        o.x = lds[HOFF + 0 * 1024 + r * 128 + c2];
        o.y = lds[HOFF + 1 * 1024 + r * 128 + c2];
        o.z = lds[HOFF + 2 * 1024 + r * 128 + c2];
        o.w = lds[HOFF + 3 * 1024 + r * 128 + c2];
        dst4[((((b << 8) + (y0 + r)) << 8) + (x0 + c2)) * 16 + cg] = o;
    }
}

extern "C" void kernel_launch(void* const* d_in, const int* in_sizes, int n_in,
                              void* d_out, int out_size, void* d_ws, size_t ws_size,
                              hipStream_t stream) {
    const float* x  = (const float*)d_in[0];
    const float* wg = (const float*)d_in[1];
    const float* wh = (const float*)d_in[2];
    float* out = (float*)d_out;
    float* ws  = (float*)d_ws;

    dim3 grid(8 * 32 * 2 * 16); // 8192: b x ystrip x xstrip x channel-group
    dim3 block(512);

    const float* src = x;
    for (int it = 0; it < 8; ++it) {
        float* dst = (it & 1) ? out : ws;
        gated_step<<<grid, block, 0, stream>>>(src, wg, wh, dst);
        src = dst;
    }
}